// Round 10
// baseline (753.366 us; speedup 1.0000x reference)
//
#include <hip/hip_runtime.h>

typedef float v2f __attribute__((ext_vector_type(2)));

#define T_LEN 2048
#define NH    10
#define OUT_T 1439
#define TFIRST 608      // first output timestep: out[k] = fc(h1(TFIRST+k))
#define NSEQ  4096
#define CH    32        // steps per hand-off chunk
#define NCH   (T_LEN / CH)      // 64
#define MFIRST (TFIRST / CH)    // 19 (exact)

#define KSIG (-1.4426950408889634f)   // -log2(e)      (sigmoid arg scale)
#define KTAN (-2.8853900817779268f)   // -2*log2(e)    (tanh arg scale)

static __device__ __forceinline__ v2f fma2(v2f a, v2f b, v2f c) {
  return __builtin_elementwise_fma(a, b, c);
}
static __device__ __forceinline__ v2f splat2(float v) { v2f r; r.x = v; r.y = v; return r; }
static __device__ __forceinline__ v2f mulsp(v2f a, float s) { v2f r; r.x = a.x*s; r.y = a.y*s; return r; }
static __device__ __forceinline__ float rcp1p(float e) {   // rcp(1+e)
  return __builtin_amdgcn_rcpf(1.0f + e);
}

// Broadcast lane (16-group base + j) to all lanes of its 16-group
// (verified R2-R8): BitMode src = ((i & 0x10) | j) within each 32-half.
#define SWZB(v, j) __uint_as_float(__builtin_amdgcn_ds_swizzle( \
    (int)__float_as_uint(v), (((j) << 5) | 0x10)))

// DPP row_ror:N within rows of 16 (verified R1-R8): dest[i] = src[(i-N)&15]
#define ROR_F(v, N) __uint_as_float(__builtin_amdgcn_update_dpp( \
    0, (int)__float_as_uint(v), 0x120 + (N), 0xF, 0xF, true))

// 2-WAVE BALANCED PIPELINE (R8 structure + R9 chain cuts):
//   Wave A: layer-0 recurrence -> h0buf (write is fire-and-forget for B),
//           PLUS the fc head (reads h1buf two chunks back).
//   Wave B: layer-1 recurrence -> h1buf, one chunk behind A.
//   R9: each wave's OWN next-step h comes from 10 independent ds_swizzle
//   crossbar broadcasts on the just-computed register (no write->readback
//   round trip on the chain); the LDS write only feeds the other wave.
//   CH=32 halves barrier rounds; 4-step sub-blocks keep I-cache and
//   register indexing static.
//   Round r: A does L0 chunk r + fc chunk r-2; B does L1 chunk r-1.
//   Parity: A writes h0[r&1]; B reads h0[(r-1)&1], writes h1[(r-1)&1];
//   A's fc reads h1[(r-2)&1] = h1[r&1]. One __syncthreads per round.
__global__ void __launch_bounds__(128, 2)
lstm_fused(const float* __restrict__ x,
           const float* __restrict__ w_ih0, const float* __restrict__ w_hh0,
           const float* __restrict__ b_ih0, const float* __restrict__ b_hh0,
           const float* __restrict__ w_ih1, const float* __restrict__ w_hh1,
           const float* __restrict__ b_ih1, const float* __restrict__ b_hh1,
           const float* __restrict__ fc1_w, const float* __restrict__ fc1_b,
           const float* __restrict__ fc2_w, const float* __restrict__ fc2_b,
           float* __restrict__ out)
{
  __shared__ __align__(16) float h0buf[2][CH][64];
  __shared__ __align__(16) float h1buf[2][CH][64];

  const int tid  = threadIdx.x;       // 0..127
  const int wid  = tid >> 6;          // 0=A(L0+FC) 1=B(L1)
  const int lane = tid & 63;
  const int grp  = lane >> 4;         // sequence within wave (0..3)
  const int u    = lane & 15;         // unit slot within group
  const int seq  = (int)blockIdx.x * 4 + grp;

  v2f wIF[NH], wGO[NH], vIF[NH], vGO[NH];
  v2f wx_if, wx_go, bb_if, bb_go;
  wx_if = wx_go = bb_if = bb_go = splat2(0.f);
#pragma unroll
  for (int j = 0; j < NH; ++j) {
    wIF[j] = splat2(0.f); wGO[j] = splat2(0.f);
    vIF[j] = splat2(0.f); vGO[j] = splat2(0.f);
  }
  float fcw[NH];
#pragma unroll
  for (int j = 0; j < NH; ++j) fcw[j] = 0.f;
  float fcb = 0.f, fc2w2 = 0.f, fc2wn = 0.f;
  const float fc2bl = fc2_b[0];

  if (wid == 0) {
    if (u < NH) {
      const int ri = 0*NH+u, rf = 1*NH+u, rg = 2*NH+u, ro = 3*NH+u;
      wx_if.x = KSIG * w_ih0[ri];            wx_if.y = KSIG * w_ih0[rf];
      wx_go.x = KTAN * w_ih0[rg];            wx_go.y = KSIG * w_ih0[ro];
      bb_if.x = KSIG * (b_ih0[ri] + b_hh0[ri]); bb_if.y = KSIG * (b_ih0[rf] + b_hh0[rf]);
      bb_go.x = KTAN * (b_ih0[rg] + b_hh0[rg]); bb_go.y = KSIG * (b_ih0[ro] + b_hh0[ro]);
#pragma unroll
      for (int j = 0; j < NH; ++j) {
        wIF[j].x = KSIG * w_hh0[ri*NH+j]; wIF[j].y = KSIG * w_hh0[rf*NH+j];
        wGO[j].x = KTAN * w_hh0[rg*NH+j]; wGO[j].y = KSIG * w_hh0[ro*NH+j];
      }
    }
    if (u < 6) {                 // fc head: fc1 row scaled by KTAN; fc2 folded
      fcb = KTAN * fc1_b[u];
      const float w2 = fc2_w[u];
      fc2w2 = 2.f * w2; fc2wn = -w2;
#pragma unroll
      for (int j = 0; j < NH; ++j) fcw[j] = KTAN * fc1_w[u*NH + j];
    }
  } else {
    if (u < NH) {
      const int ri = 0*NH+u, rf = 1*NH+u, rg = 2*NH+u, ro = 3*NH+u;
      bb_if.x = KSIG * (b_ih1[ri] + b_hh1[ri]); bb_if.y = KSIG * (b_ih1[rf] + b_hh1[rf]);
      bb_go.x = KTAN * (b_ih1[rg] + b_hh1[rg]); bb_go.y = KSIG * (b_ih1[ro] + b_hh1[ro]);
#pragma unroll
      for (int j = 0; j < NH; ++j) {
        wIF[j].x = KSIG * w_ih1[ri*NH+j]; wIF[j].y = KSIG * w_ih1[rf*NH+j];
        wGO[j].x = KTAN * w_ih1[rg*NH+j]; wGO[j].y = KSIG * w_ih1[ro*NH+j];
        vIF[j].x = KSIG * w_hh1[ri*NH+j]; vIF[j].y = KSIG * w_hh1[rf*NH+j];
        vGO[j].x = KTAN * w_hh1[rg*NH+j]; vGO[j].y = KSIG * w_hh1[ro*NH+j];
      }
    }
  }

  const float* xp   = x + (size_t)seq * T_LEN;
  float*       outp = out + (size_t)seq * OUT_T;

  float c = 0.f;                                  // KTAN-scaled cell state
  float r0=0.f,r1=0.f,r2=0.f,r3=0.f,r4=0.f,r5=0.f,r6=0.f,r7=0.f,r8=0.f,r9=0.f;

  // ---- one L0 step: gates from (xv, r*) -> h0; write for B; swizzle self ----
  auto l0_step = [&](float xv, float* dst) {
    v2f aA = fma2(wx_if, splat2(xv), bb_if);
    v2f gA = fma2(wx_go, splat2(xv), bb_go);
    v2f aB = mulsp(wIF[1], r1);
    v2f gB = mulsp(wGO[1], r1);
#define L0T(j, hv) { const v2f sp = splat2(hv); \
    ((j & 1) ? aB : aA) = fma2(wIF[j], sp, ((j & 1) ? aB : aA)); \
    ((j & 1) ? gB : gA) = fma2(wGO[j], sp, ((j & 1) ? gB : gA)); }
    L0T(0,r0) L0T(2,r2) L0T(3,r3) L0T(4,r4) L0T(5,r5)
    L0T(6,r6) L0T(7,r7) L0T(8,r8) L0T(9,r9)
#undef L0T
    const v2f gif = aA + aB;
    const v2f ggo = gA + gB;
    const float si = rcp1p(__builtin_amdgcn_exp2f(gif.x));
    const float sf = rcp1p(__builtin_amdgcn_exp2f(gif.y));
    const float rg = rcp1p(__builtin_amdgcn_exp2f(ggo.x));
    const float so = rcp1p(__builtin_amdgcn_exp2f(ggo.y));
    const float tgp = __builtin_fmaf(rg, 2.f*KTAN, -KTAN);  // KTAN*tanh(g)
    c = __builtin_fmaf(sf, c, si * tgp);                    // c' = KTAN*c
    const float rc = rcp1p(__builtin_amdgcn_exp2f(c));
    const float tc = __builtin_fmaf(rc, 2.f, -1.f);         // tanh(c)
    const float h0n = so * tc;                              // true h0
    *dst = h0n;                                             // off-chain (for B)
    r0 = SWZB(h0n,0); r1 = SWZB(h0n,1); r2 = SWZB(h0n,2); r3 = SWZB(h0n,3);
    r4 = SWZB(h0n,4); r5 = SWZB(h0n,5); r6 = SWZB(h0n,6); r7 = SWZB(h0n,7);
    r8 = SWZB(h0n,8); r9 = SWZB(h0n,9);
  };

  auto a_chunk = [&](int m) {
    float* hb = &h0buf[m & 1][0][0] + lane;
    const float4* xq = (const float4*)(xp + m * CH);
#pragma unroll 1
    for (int b = 0; b < CH / 4; ++b) {
      const float4 xb = xq[b];
      float* d = hb + b * 256;
      l0_step(xb.x, d);
      l0_step(xb.y, d + 64);
      l0_step(xb.z, d + 128);
      l0_step(xb.w, d + 192);
    }
  };

  // ---- one L1 step: gates from (h0 LDS reads, r*) -> h1; write; swizzle ----
  auto l1_step = [&](const float* hp, float* dst) {
    const float4 pa = *(const float4*)(hp);
    const float4 pb = *(const float4*)(hp + 4);
    const float2 pc = *(const float2*)(hp + 8);
    v2f cA = fma2(wIF[0], splat2(pa.x), bb_if);
    v2f hA = fma2(wGO[0], splat2(pa.x), bb_go);
    v2f cB = mulsp(wIF[1], pa.y);
    v2f hB = mulsp(wGO[1], pa.y);
#define L1I(j, hv, AC, GC) { const v2f sp = splat2(hv); \
    AC = fma2(wIF[j], sp, AC); GC = fma2(wGO[j], sp, GC); }
    L1I(2,pa.z,cA,hA) L1I(3,pa.w,cB,hB) L1I(4,pb.x,cA,hA) L1I(5,pb.y,cB,hB)
    L1I(6,pb.z,cA,hA) L1I(7,pb.w,cB,hB) L1I(8,pc.x,cA,hA) L1I(9,pc.y,cB,hB)
#undef L1I
    v2f cC = mulsp(vIF[0], r0);
    v2f hC = mulsp(vGO[0], r0);
    v2f cD = mulsp(vIF[1], r1);
    v2f hD = mulsp(vGO[1], r1);
#define L1R(j, hv, AC, GC) { const v2f sp = splat2(hv); \
    AC = fma2(vIF[j], sp, AC); GC = fma2(vGO[j], sp, GC); }
    L1R(2,r2,cC,hC) L1R(3,r3,cD,hD) L1R(4,r4,cC,hC) L1R(5,r5,cD,hD)
    L1R(6,r6,cC,hC) L1R(7,r7,cD,hD) L1R(8,r8,cC,hC) L1R(9,r9,cD,hD)
#undef L1R
    const v2f gif = (cA + cB) + (cC + cD);
    const v2f ggo = (hA + hB) + (hC + hD);
    const float si = rcp1p(__builtin_amdgcn_exp2f(gif.x));
    const float sf = rcp1p(__builtin_amdgcn_exp2f(gif.y));
    const float rg = rcp1p(__builtin_amdgcn_exp2f(ggo.x));
    const float so = rcp1p(__builtin_amdgcn_exp2f(ggo.y));
    const float tgp = __builtin_fmaf(rg, 2.f*KTAN, -KTAN);
    c = __builtin_fmaf(sf, c, si * tgp);
    const float rc = rcp1p(__builtin_amdgcn_exp2f(c));
    const float tc = __builtin_fmaf(rc, 2.f, -1.f);
    const float h1n = so * tc;                              // true h1
    *dst = h1n;                                             // off-chain (for fc)
    r0 = SWZB(h1n,0); r1 = SWZB(h1n,1); r2 = SWZB(h1n,2); r3 = SWZB(h1n,3);
    r4 = SWZB(h1n,4); r5 = SWZB(h1n,5); r6 = SWZB(h1n,6); r7 = SWZB(h1n,7);
    r8 = SWZB(h1n,8); r9 = SWZB(h1n,9);
  };

  auto b_chunk = [&](int m) {
    const float* hbi = &h0buf[m & 1][0][grp * 16];
    float* ob = &h1buf[m & 1][0][0] + lane;
#pragma unroll 1
    for (int b = 0; b < CH / 4; ++b) {
      const float* hp = hbi + b * 256;
      float* d = ob + b * 256;
      l1_step(hp,       d);
      l1_step(hp + 64,  d + 64);
      l1_step(hp + 128, d + 128);
      l1_step(hp + 192, d + 192);
    }
  };

  // ---- fc head (wave A) on h1 chunk m, two rounds behind ----
  auto fc_chunk = [&](int m) {
    const float* hb = &h1buf[m & 1][0][grp * 16];
    float* oq = outp + (m * CH - TFIRST);
    const int tbase = m * CH;
#pragma unroll 1
    for (int b = 0; b < CH / 4; ++b) {
      const float* hp = hb + b * 256;
#pragma unroll
      for (int k = 0; k < 4; ++k) {
        const int s = b * 4 + k;
        if (tbase + s < TFIRST + OUT_T) {         // t <= 2046
          const float4 pa = *(const float4*)(hp + k*64);
          const float4 pb = *(const float4*)(hp + k*64 + 4);
          const float2 pc = *(const float2*)(hp + k*64 + 8);
          float acc = __builtin_fmaf(pa.x, fcw[0], fcb);    // KTAN-scaled
          acc = __builtin_fmaf(pa.y, fcw[1], acc);
          acc = __builtin_fmaf(pa.z, fcw[2], acc);
          acc = __builtin_fmaf(pa.w, fcw[3], acc);
          acc = __builtin_fmaf(pb.x, fcw[4], acc);
          acc = __builtin_fmaf(pb.y, fcw[5], acc);
          acc = __builtin_fmaf(pb.z, fcw[6], acc);
          acc = __builtin_fmaf(pb.w, fcw[7], acc);
          acc = __builtin_fmaf(pc.x, fcw[8], acc);
          acc = __builtin_fmaf(pc.y, fcw[9], acc);
          const float rc = rcp1p(__builtin_amdgcn_exp2f(acc));
          float y = __builtin_fmaf(rc, fc2w2, fc2wn);       // fc2_w*tanh(acc)
          y += ROR_F(y, 8);
          y += ROR_F(y, 4);
          y += ROR_F(y, 2);
          y += ROR_F(y, 1);                       // whole 16-group holds sum
          if (u == 0) oq[s] = y + fc2bl;
        }
      }
    }
  };

  // ---- pipeline: round r = {A: L0 chunk r, fc chunk r-2 ; B: L1 chunk r-1} ----
#pragma unroll 1
  for (int r = 0; r < NCH + 2; ++r) {
    if (wid == 0) {
      if (r < NCH) a_chunk(r);
      const int m = r - 2;
      if (m >= MFIRST && m < NCH) fc_chunk(m);
    } else {
      if (r >= 1 && r <= NCH) b_chunk(r - 1);
    }
    __syncthreads();
  }
}

extern "C" void kernel_launch(void* const* d_in, const int* in_sizes, int n_in,
                              void* d_out, int out_size, void* d_ws, size_t ws_size,
                              hipStream_t stream) {
  const float* x     = (const float*)d_in[0];
  const float* w_ih0 = (const float*)d_in[1];
  const float* w_hh0 = (const float*)d_in[2];
  const float* b_ih0 = (const float*)d_in[3];
  const float* b_hh0 = (const float*)d_in[4];
  const float* w_ih1 = (const float*)d_in[5];
  const float* w_hh1 = (const float*)d_in[6];
  const float* b_ih1 = (const float*)d_in[7];
  const float* b_hh1 = (const float*)d_in[8];
  const float* fc1_w = (const float*)d_in[9];
  const float* fc1_b = (const float*)d_in[10];
  const float* fc2_w = (const float*)d_in[11];
  const float* fc2_b = (const float*)d_in[12];
  float* out = (float*)d_out;

  lstm_fused<<<dim3(NSEQ / 4), dim3(128), 0, stream>>>(
      x, w_ih0, w_hh0, b_ih0, b_hh0, w_ih1, w_hh1, b_ih1, b_hh1,
      fc1_w, fc1_b, fc2_w, fc2_b, out);
}